// Round 1
// baseline (763.812 us; speedup 1.0000x reference)
//
#include <hip/hip_runtime.h>
#include <hip/hip_bf16.h>
#include <cstdint>

// Problem constants (from reference): N=4096 tokens, D=1024, H=2048, E=8, TOP_K=2
#define N_TOK 4096
#define DIM   1024
#define HID   2048
#define NE    8

typedef __bf16 bf16x8 __attribute__((ext_vector_type(8)));
typedef __bf16 bf16x4 __attribute__((ext_vector_type(4)));
typedef float  f32x4  __attribute__((ext_vector_type(4)));

// ---------------------------------------------------------------------------
// x fp32 -> bf16 (row-major, no transpose)
// ---------------------------------------------------------------------------
__global__ void cvt_x_kernel(const float* __restrict__ x, __bf16* __restrict__ xb) {
    const int i = (blockIdx.x * 256 + threadIdx.x) * 4;
    float4 v = *(const float4*)&x[i];
    bf16x4 o = { (__bf16)v.x, (__bf16)v.y, (__bf16)v.z, (__bf16)v.w };
    *(bf16x4*)&xb[i] = o;
}

// ---------------------------------------------------------------------------
// Per-expert transpose + fp32->bf16: src [E][R][C] -> dst [E][C][R]
// 32x32 tiles via LDS (pad 33 to kill bank conflicts)
// ---------------------------------------------------------------------------
__global__ void transpose_cvt_kernel(const float* __restrict__ src, __bf16* __restrict__ dst,
                                     int R, int C) {
    const size_t eoff = (size_t)blockIdx.z * R * C;
    src += eoff; dst += eoff;
    __shared__ float t[32][33];
    const int r0 = blockIdx.x * 32, c0 = blockIdx.y * 32;
    const int tr = threadIdx.x >> 3;          // 0..31
    const int tc = (threadIdx.x & 7) * 4;     // 0,4,..,28
    float4 v = *(const float4*)&src[(size_t)(r0 + tr) * C + c0 + tc];
    t[tr][tc + 0] = v.x; t[tr][tc + 1] = v.y; t[tr][tc + 2] = v.z; t[tr][tc + 3] = v.w;
    __syncthreads();
    bf16x4 o;
    o[0] = (__bf16)t[tc + 0][tr];
    o[1] = (__bf16)t[tc + 1][tr];
    o[2] = (__bf16)t[tc + 2][tr];
    o[3] = (__bf16)t[tc + 3][tr];
    *(bf16x4*)&dst[(size_t)(c0 + tr) * R + r0 + tc] = o;
}

// ---------------------------------------------------------------------------
// Gating: fp32 logits = x @ gate_W + gate_b, softmax, top-2 (jax tie-break:
// strict > keeps lowest index). One wave per token.
// ---------------------------------------------------------------------------
__global__ void gate_kernel(const float* __restrict__ x, const float* __restrict__ gW,
                            const float* __restrict__ gb, int* __restrict__ top_idx,
                            float* __restrict__ top_gate, int* __restrict__ cnt) {
    const int tokn = blockIdx.x * 4 + (threadIdx.x >> 6);
    const int lane = threadIdx.x & 63;
    const float* xr = x + (size_t)tokn * DIM;
    float acc[NE] = {};
    for (int i = 0; i < DIM / 64; i++) {
        const int d = lane + i * 64;
        const float xv = xr[d];
        const float4 w0 = *(const float4*)&gW[d * NE];
        const float4 w1 = *(const float4*)&gW[d * NE + 4];
        acc[0] += xv * w0.x; acc[1] += xv * w0.y; acc[2] += xv * w0.z; acc[3] += xv * w0.w;
        acc[4] += xv * w1.x; acc[5] += xv * w1.y; acc[6] += xv * w1.z; acc[7] += xv * w1.w;
    }
#pragma unroll
    for (int e = 0; e < NE; e++)
#pragma unroll
        for (int s = 32; s > 0; s >>= 1)
            acc[e] += __shfl_down(acc[e], s, 64);
    if (lane == 0) {
        float lg[NE], p[NE];
        float mx = -1e30f;
#pragma unroll
        for (int e = 0; e < NE; e++) { lg[e] = acc[e] + gb[e]; mx = fmaxf(mx, lg[e]); }
        float s = 0.f;
#pragma unroll
        for (int e = 0; e < NE; e++) { p[e] = __expf(lg[e] - mx); s += p[e]; }
        const float inv = 1.f / s;
#pragma unroll
        for (int e = 0; e < NE; e++) p[e] *= inv;
        int i0 = 0; float p0 = p[0];
#pragma unroll
        for (int e = 1; e < NE; e++) if (p[e] > p0) { p0 = p[e]; i0 = e; }
        int i1 = -1; float p1 = -1.f;
#pragma unroll
        for (int e = 0; e < NE; e++) if (e != i0 && p[e] > p1) { p1 = p[e]; i1 = e; }
        top_idx[tokn * 2] = i0;  top_idx[tokn * 2 + 1] = i1;
        top_gate[tokn * 2] = p0; top_gate[tokn * 2 + 1] = p1;
        atomicAdd(&cnt[i0], 1);  atomicAdd(&cnt[i1], 1);
    }
}

// Exclusive prefix over 8 expert counts.
__global__ void scan_kernel(const int* __restrict__ cnt, int* __restrict__ offs) {
    if (threadIdx.x == 0) {
        int s = 0;
        for (int e = 0; e < NE; e++) { offs[e] = s; s += cnt[e]; }
        offs[NE] = s;
    }
}

// Build compact per-expert row lists: row_token[r], row_gate[r], r in [0, 2N).
__global__ void build_kernel(const int* __restrict__ top_idx, const float* __restrict__ top_gate,
                             const int* __restrict__ offs, int* __restrict__ run,
                             int* __restrict__ row_token, float* __restrict__ row_gate) {
    const int n = blockIdx.x * 256 + threadIdx.x;
    if (n >= N_TOK) return;
#pragma unroll
    for (int k = 0; k < 2; k++) {
        const int e = top_idx[n * 2 + k];
        const int pos = atomicAdd(&run[e], 1);
        const int r = offs[e] + pos;
        row_token[r] = n;
        row_gate[r]  = top_gate[n * 2 + k];
    }
}

// ---------------------------------------------------------------------------
// Grouped GEMM1: h[r][:] = relu(x[tok(r)] @ W1[e] + b1[e]), bf16 out.
// 128x128 tile, BK=32, 4 waves (2x2), 16x16x32 bf16 MFMA, LDS pad to 40.
// ---------------------------------------------------------------------------
__global__ __launch_bounds__(256, 2) void gemm1_kernel(
    const __bf16* __restrict__ xb, const __bf16* __restrict__ w1t,
    const float* __restrict__ b1, const int* __restrict__ cnt,
    const int* __restrict__ offs, const int* __restrict__ row_token,
    __bf16* __restrict__ h) {
    const int e  = blockIdx.x >> 5;
    const int mt = blockIdx.x & 31;
    const int ce = cnt[e];
    if (mt * 128 >= ce) return;
    const int off_e = offs[e];
    const int n0 = blockIdx.y * 128;

    __shared__ __bf16 lA[128 * 40];
    __shared__ __bf16 lB[128 * 40];

    const int tid  = threadIdx.x;
    const int trow = tid >> 1;
    const int tk   = (tid & 1) << 4;

    const int gr  = off_e + mt * 128 + trow;
    const int grc = gr < 2 * N_TOK - 1 ? gr : 2 * N_TOK - 1;
    const int tok = row_token[grc] & (N_TOK - 1);   // mask => always a valid token row

    const __bf16* aptr = xb  + (size_t)tok * DIM + tk;
    const __bf16* bptr = w1t + ((size_t)e * HID + n0 + trow) * DIM + tk;

    uint4 ra0 = *(const uint4*)(aptr);
    uint4 ra1 = *(const uint4*)(aptr + 8);
    uint4 rb0 = *(const uint4*)(bptr);
    uint4 rb1 = *(const uint4*)(bptr + 8);

    const int lane = tid & 63;
    const int quad = lane >> 4;
    const int l16  = lane & 15;
    const int wid  = tid >> 6;
    const int wm   = wid & 1;
    const int wn   = wid >> 1;

    f32x4 acc[4][4] = {};

    for (int kk = 0; kk < DIM; kk += 32) {
        __syncthreads();
        *(uint4*)&lA[trow * 40 + tk]     = ra0;
        *(uint4*)&lA[trow * 40 + tk + 8] = ra1;
        *(uint4*)&lB[trow * 40 + tk]     = rb0;
        *(uint4*)&lB[trow * 40 + tk + 8] = rb1;
        __syncthreads();
        if (kk + 32 < DIM) {   // prefetch next K-slab, overlaps the MFMAs below
            ra0 = *(const uint4*)(aptr + kk + 32);
            ra1 = *(const uint4*)(aptr + kk + 40);
            rb0 = *(const uint4*)(bptr + kk + 32);
            rb1 = *(const uint4*)(bptr + kk + 40);
        }
        bf16x8 af[4], bfr[4];
#pragma unroll
        for (int mi = 0; mi < 4; mi++)
            af[mi] = *(const bf16x8*)&lA[(wm * 64 + mi * 16 + l16) * 40 + quad * 8];
#pragma unroll
        for (int ni = 0; ni < 4; ni++)
            bfr[ni] = *(const bf16x8*)&lB[(wn * 64 + ni * 16 + l16) * 40 + quad * 8];
#pragma unroll
        for (int mi = 0; mi < 4; mi++)
#pragma unroll
            for (int ni = 0; ni < 4; ni++)
                acc[mi][ni] = __builtin_amdgcn_mfma_f32_16x16x32_bf16(af[mi], bfr[ni], acc[mi][ni], 0, 0, 0);
    }

#pragma unroll
    for (int ni = 0; ni < 4; ni++) {
        const int col = n0 + wn * 64 + ni * 16 + l16;
        const float bias = b1[e * HID + col];
#pragma unroll
        for (int mi = 0; mi < 4; mi++) {
#pragma unroll
            for (int r = 0; r < 4; r++) {
                const int lr = wm * 64 + mi * 16 + quad * 4 + r;
                const int gm = mt * 128 + lr;
                if (gm < ce) {
                    float v = acc[mi][ni][r] + bias;
                    v = v > 0.f ? v : 0.f;
                    h[(size_t)(off_e + gm) * HID + col] = (__bf16)v;
                }
            }
        }
    }
}

// ---------------------------------------------------------------------------
// Grouped GEMM2: y[r][:] = h[r] @ W2[e] + b2[e]; out[tok(r)] += gate(r) * y.
// ---------------------------------------------------------------------------
__global__ __launch_bounds__(256, 2) void gemm2_kernel(
    const __bf16* __restrict__ h, const __bf16* __restrict__ w2t,
    const float* __restrict__ b2, const int* __restrict__ cnt,
    const int* __restrict__ offs, const int* __restrict__ row_token,
    const float* __restrict__ row_gate, float* __restrict__ out) {
    const int e  = blockIdx.x >> 5;
    const int mt = blockIdx.x & 31;
    const int ce = cnt[e];
    if (mt * 128 >= ce) return;
    const int off_e = offs[e];
    const int n0 = blockIdx.y * 128;

    __shared__ __bf16 lA[128 * 40];
    __shared__ __bf16 lB[128 * 40];

    const int tid  = threadIdx.x;
    const int trow = tid >> 1;
    const int tk   = (tid & 1) << 4;

    const int gr = off_e + mt * 128 + trow;
    const int hr = gr < 2 * N_TOK - 1 ? gr : 2 * N_TOK - 1;   // clamp inside h buffer

    const __bf16* aptr = h   + (size_t)hr * HID + tk;
    const __bf16* bptr = w2t + ((size_t)e * DIM + n0 + trow) * HID + tk;

    uint4 ra0 = *(const uint4*)(aptr);
    uint4 ra1 = *(const uint4*)(aptr + 8);
    uint4 rb0 = *(const uint4*)(bptr);
    uint4 rb1 = *(const uint4*)(bptr + 8);

    const int lane = tid & 63;
    const int quad = lane >> 4;
    const int l16  = lane & 15;
    const int wid  = tid >> 6;
    const int wm   = wid & 1;
    const int wn   = wid >> 1;

    f32x4 acc[4][4] = {};

    for (int kk = 0; kk < HID; kk += 32) {
        __syncthreads();
        *(uint4*)&lA[trow * 40 + tk]     = ra0;
        *(uint4*)&lA[trow * 40 + tk + 8] = ra1;
        *(uint4*)&lB[trow * 40 + tk]     = rb0;
        *(uint4*)&lB[trow * 40 + tk + 8] = rb1;
        __syncthreads();
        if (kk + 32 < HID) {
            ra0 = *(const uint4*)(aptr + kk + 32);
            ra1 = *(const uint4*)(aptr + kk + 40);
            rb0 = *(const uint4*)(bptr + kk + 32);
            rb1 = *(const uint4*)(bptr + kk + 40);
        }
        bf16x8 af[4], bfr[4];
#pragma unroll
        for (int mi = 0; mi < 4; mi++)
            af[mi] = *(const bf16x8*)&lA[(wm * 64 + mi * 16 + l16) * 40 + quad * 8];
#pragma unroll
        for (int ni = 0; ni < 4; ni++)
            bfr[ni] = *(const bf16x8*)&lB[(wn * 64 + ni * 16 + l16) * 40 + quad * 8];
#pragma unroll
        for (int mi = 0; mi < 4; mi++)
#pragma unroll
            for (int ni = 0; ni < 4; ni++)
                acc[mi][ni] = __builtin_amdgcn_mfma_f32_16x16x32_bf16(af[mi], bfr[ni], acc[mi][ni], 0, 0, 0);
    }

#pragma unroll
    for (int mi = 0; mi < 4; mi++) {
#pragma unroll
        for (int r = 0; r < 4; r++) {
            const int lr = wm * 64 + mi * 16 + quad * 4 + r;
            const int gm = mt * 128 + lr;
            if (gm < ce) {
                const int rr  = off_e + gm;
                const int tok = row_token[rr];
                const float g = row_gate[rr];
#pragma unroll
                for (int ni = 0; ni < 4; ni++) {
                    const int col = n0 + wn * 64 + ni * 16 + l16;
                    const float v = acc[mi][ni][r] + b2[e * DIM + col];
                    atomicAdd(&out[(size_t)tok * DIM + col], g * v);
                }
            }
        }
    }
}

// ---------------------------------------------------------------------------
extern "C" void kernel_launch(void* const* d_in, const int* in_sizes, int n_in,
                              void* d_out, int out_size, void* d_ws, size_t ws_size,
                              hipStream_t stream) {
    const float* x  = (const float*)d_in[0];
    const float* gW = (const float*)d_in[1];
    const float* gb = (const float*)d_in[2];
    const float* W1 = (const float*)d_in[3];
    const float* b1 = (const float*)d_in[4];
    const float* W2 = (const float*)d_in[5];
    const float* b2 = (const float*)d_in[6];
    float* out = (float*)d_out;

    char* ws = (char*)d_ws;
    // ws layout (bytes):
    //   [0, 8 MiB)    xb   : x as bf16            [N][D]
    //   [8, 40 MiB)   w1t  : W1^T bf16            [E][H][D]
    //   [40, 72 MiB)  w2t  : W2^T bf16            [E][D][H]
    //   [72, 104 MiB) h    : hidden bf16          [2N][H]
    //   [104 MiB..)   row_token/row_gate/top_idx/top_gate/cnt/offs/run
    __bf16* xb   = (__bf16*)(ws);
    __bf16* w1t  = (__bf16*)(ws + ((size_t)8  << 20));
    __bf16* w2t  = (__bf16*)(ws + ((size_t)40 << 20));
    __bf16* hbuf = (__bf16*)(ws + ((size_t)72 << 20));
    char* tail   = ws + ((size_t)104 << 20);
    int*   row_token = (int*)(tail);
    float* row_gate  = (float*)(tail + 32768);
    int*   top_idx   = (int*)(tail + 65536);
    float* top_gate  = (float*)(tail + 98304);
    int*   cnt       = (int*)(tail + 131072);
    int*   offs      = cnt + 16;
    int*   run       = cnt + 32;

    hipMemsetAsync(cnt, 0, 256, stream);
    hipMemsetAsync(d_out, 0, (size_t)N_TOK * DIM * sizeof(float), stream);

    cvt_x_kernel<<<N_TOK * DIM / 4 / 256, 256, 0, stream>>>(x, xb);
    transpose_cvt_kernel<<<dim3(DIM / 32, HID / 32, NE), 256, 0, stream>>>(W1, w1t, DIM, HID);
    transpose_cvt_kernel<<<dim3(HID / 32, DIM / 32, NE), 256, 0, stream>>>(W2, w2t, HID, DIM);
    gate_kernel<<<N_TOK / 4, 256, 0, stream>>>(x, gW, gb, top_idx, top_gate, cnt);
    scan_kernel<<<1, 64, 0, stream>>>(cnt, offs);
    build_kernel<<<N_TOK / 256, 256, 0, stream>>>(top_idx, top_gate, offs, run, row_token, row_gate);
    gemm1_kernel<<<dim3(NE * 32, HID / 128), 256, 0, stream>>>(xb, w1t, b1, cnt, offs, row_token, hbuf);
    gemm2_kernel<<<dim3(NE * 32, DIM / 128), 256, 0, stream>>>(hbuf, w2t, b2, cnt, offs, row_token, row_gate, out);
}